// Round 3
// baseline (399.955 us; speedup 1.0000x reference)
//
#include <hip/hip_runtime.h>

#define C 128
#define K 27
#define BATCHES 4
#define CHUNKS 512            // stage-A chunks per batch
#define CONV_BLOCKS 2048
#define CONV_TPB 256
#define NWAVES_CONV (CONV_BLOCKS * (CONV_TPB / 64))
#define BN_EPS 1e-5f

// ---------------------------------------------------------------- mask dtype probe
// If nbr_mask is stored as 1-byte bools, words in the early region exceed 1
// (center offset k=13 is always true; its byte position cycles within words).
// If stored as int32, every word is 0 or 1 -> flag stays 0.
__global__ void detect_mask_kernel(const unsigned int* __restrict__ w, int nwords,
                                   int* __restrict__ flag) {
  int stride = gridDim.x * blockDim.x;
  bool bad = false;
  for (int i = blockIdx.x * blockDim.x + threadIdx.x; i < nwords; i += stride)
    bad |= (w[i] > 1u);
  if (__any(bad) && (threadIdx.x & 63) == 0) atomicOr(flag, 1);
}

// ---------------------------------------------------------------- per-batch sum/max, stage A
// 256 threads: two 128-thread row-groups; each thread owns one channel.
__global__ void reduceA_kernel(const float* __restrict__ feats, float* __restrict__ psum,
                               float* __restrict__ pmax, int NPER) {
  int b = blockIdx.x / CHUNKS, chunk = blockIdx.x % CHUNKS;
  int CH = (NPER + CHUNKS - 1) / CHUNKS;
  int r0 = b * NPER + chunk * CH;
  int r1 = min(b * NPER + NPER, r0 + CH);
  int c = threadIdx.x & 127;
  int half = threadIdx.x >> 7;
  float s = 0.f, m = -INFINITY;
  for (int i = r0 + half; i < r1; i += 2) {
    float v = feats[(size_t)i * C + c];
    s += v;
    m = fmaxf(m, v);
  }
  size_t slot = (size_t)(blockIdx.x * 2 + half) * C + c;
  psum[slot] = s;
  pmax[slot] = m;
}

// ---------------------------------------------------------------- stage B
__global__ void reduceB_kernel(const float* __restrict__ psum, const float* __restrict__ pmax,
                               float* __restrict__ avg, float* __restrict__ mx, int NPER) {
  __shared__ float ssum[256], smax[256];
  int b = blockIdx.x;
  int c = threadIdx.x & 127, half = threadIdx.x >> 7;
  float s = 0.f, m = -INFINITY;
  for (int j = half; j < 2 * CHUNKS; j += 2) {
    size_t slot = (size_t)(b * 2 * CHUNKS + j) * C + c;
    s += psum[slot];
    m = fmaxf(m, pmax[slot]);
  }
  ssum[threadIdx.x] = s;
  smax[threadIdx.x] = m;
  __syncthreads();
  if (half == 0) {
    s = ssum[c] + ssum[128 + c];
    m = fmaxf(smax[c], smax[128 + c]);
    avg[b * C + c] = s / (float)NPER;
    mx[b * C + c] = m;
  }
}

// ---------------------------------------------------------------- channel-attention MLP
__global__ void mlp_kernel(const float* __restrict__ avg, const float* __restrict__ mx,
                           const float* __restrict__ w1, const float* __restrict__ b1,
                           const float* __restrict__ w2, const float* __restrict__ b2,
                           float* __restrict__ wgt) {
  int b = blockIdx.x, t = threadIdx.x;  // 128 threads
  __shared__ float h1a[64], h1m[64];
  if (t < 64) {
    float sa = b1[t], sm = b1[t];
    for (int c = 0; c < C; ++c) {
      float wv = w1[c * 64 + t];
      sa += avg[b * C + c] * wv;
      sm += mx[b * C + c] * wv;
    }
    h1a[t] = fmaxf(sa, 0.f);
    h1m[t] = fmaxf(sm, 0.f);
  }
  __syncthreads();
  float za = b2[t], zm = b2[t];
  for (int h = 0; h < 64; ++h) {
    float wv = w2[h * C + t];
    za += h1a[h] * wv;
    zm += h1m[h] * wv;
  }
  float z = za + zm;
  wgt[b * C + t] = 1.f / (1.f + expf(-z));
}

// ---------------------------------------------------------------- sparse 3x3x3 conv C->4 + BN partials
// 4 rows per wave ("quad"), 16 lanes per row, 8 channels per lane.
// Mask/idx for the 108 quad entries loaded by 2 lane-strided coalesced loads;
// per-row 27-bit windows cut from the 128-bit ballot pair.
// The gather loop trip count is made WAVE-UNIFORM (max popcount across the 4
// subgroups) so the __shfl index-distribution always executes with all 64
// lanes active — ds_bpermute reads from inactive lanes are undefined on CDNA.
__global__ __launch_bounds__(CONV_TPB) void conv_kernel(
    const float* __restrict__ feats, const float* __restrict__ wgt,
    const float* __restrict__ conv1_w, const int* __restrict__ nbr_idx,
    const void* __restrict__ nbr_mask, const int* __restrict__ flagp,
    float* __restrict__ y, float* __restrict__ bnpart, int N, int NPER) {
  int lane = threadIdx.x & 63;
  int sub = lane >> 4, cl = lane & 15;
  int gwave = blockIdx.x * (blockDim.x >> 6) + (threadIdx.x >> 6);
  int nwaves = gridDim.x * (blockDim.x >> 6);
  int Q = (N + 3) >> 2;
  int qpw = (Q + nwaves - 1) / nwaves;
  int qbeg = gwave * qpw, qend = min(Q, qbeg + qpw);
  bool byteMode = (*flagp != 0);
  long long maxE = (long long)N * K;
  const unsigned char* mb = (const unsigned char*)nbr_mask;
  const int* mi = (const int*)nbr_mask;

  float s0 = 0, s1 = 0, s2 = 0, s3 = 0, q0 = 0, q1 = 0, q2 = 0, q3 = 0;

  int b = 0;
  while (qbeg * 4 >= (b + 1) * NPER && b < BATCHES - 1) ++b;
  float4 wr0 = ((const float4*)(wgt + b * C + cl * 8))[0];
  float4 wr1 = ((const float4*)(wgt + b * C + cl * 8))[1];

  // prefetch first quad
  bool mkA = false, mkB = false;
  int idxA = 0, idxB = 0;
  if (qbeg < qend) {
    long long e0 = (long long)qbeg * (4 * K);
    long long eA = e0 + lane, eB = e0 + 64 + lane;
    if (eA < maxE) {
      mkA = byteMode ? (mb[eA] != 0) : (mi[eA] != 0);
      idxA = nbr_idx[eA];
    }
    if (lane < 4 * K - 64 && eB < maxE) {
      mkB = byteMode ? (mb[eB] != 0) : (mi[eB] != 0);
      idxB = nbr_idx[eB];
    }
  }

  for (int q = qbeg; q < qend; ++q) {
    unsigned long long balA = __ballot(mkA);
    unsigned long long balB = __ballot(mkB);
    int cIdxA = idxA, cIdxB = idxB;
    // prefetch next quad
    mkA = false; mkB = false;
    if (q + 1 < qend) {
      long long e0 = (long long)(q + 1) * (4 * K);
      long long eA = e0 + lane, eB = e0 + 64 + lane;
      if (eA < maxE) {
        mkA = byteMode ? (mb[eA] != 0) : (mi[eA] != 0);
        idxA = nbr_idx[eA];
      }
      if (lane < 4 * K - 64 && eB < maxE) {
        mkB = byteMode ? (mb[eB] != 0) : (mi[eB] != 0);
        idxB = nbr_idx[eB];
      }
    }
    int i0 = q * 4;
    if (i0 >= (b + 1) * NPER && b < BATCHES - 1) {
      ++b;
      wr0 = ((const float4*)(wgt + b * C + cl * 8))[0];
      wr1 = ((const float4*)(wgt + b * C + cl * 8))[1];
    }
    unsigned w0 = (unsigned)(balA & 0x7FFFFFFull);
    unsigned w1 = (unsigned)((balA >> 27) & 0x7FFFFFFull);
    unsigned w2 = (unsigned)(((balA >> 54) | (balB << 10)) & 0x7FFFFFFull);
    unsigned w3 = (unsigned)((balB >> 17) & 0x7FFFFFFull);
    unsigned bal = sub == 0 ? w0 : sub == 1 ? w1 : sub == 2 ? w2 : w3;
    int cnt = __popc(bal);
    int mc = cnt;
    mc = max(mc, __shfl_xor(mc, 16));
    mc = max(mc, __shfl_xor(mc, 32));
    float a0 = 0, a1 = 0, a2 = 0, a3 = 0;
    for (int t = 0; t < mc; ++t) {
      int kk = __ffs(bal) - 1;     // -1 once this subgroup is exhausted
      bal &= bal - 1;              // 0 stays 0
      int src = kk >= 0 ? sub * K + kk : 0;
      // all 64 lanes active for both shuffles (mc is wave-uniform)
      int jA = __shfl(cIdxA, src & 63);
      int jB = __shfl(cIdxB, (src - 64) & 63);
      if (t < cnt) {
        int j = src < 64 ? jA : jB;
        const float4* fp = (const float4*)(feats + (size_t)j * C);
        float4 f0 = fp[2 * cl];
        float4 f1 = fp[2 * cl + 1];
        const float4* wp = (const float4*)(conv1_w + ((size_t)kk * C + cl * 8) * 4);
        float m;
        float4 W;
        m = f0.x * wr0.x; W = wp[0]; a0 += m * W.x; a1 += m * W.y; a2 += m * W.z; a3 += m * W.w;
        m = f0.y * wr0.y; W = wp[1]; a0 += m * W.x; a1 += m * W.y; a2 += m * W.z; a3 += m * W.w;
        m = f0.z * wr0.z; W = wp[2]; a0 += m * W.x; a1 += m * W.y; a2 += m * W.z; a3 += m * W.w;
        m = f0.w * wr0.w; W = wp[3]; a0 += m * W.x; a1 += m * W.y; a2 += m * W.z; a3 += m * W.w;
        m = f1.x * wr1.x; W = wp[4]; a0 += m * W.x; a1 += m * W.y; a2 += m * W.z; a3 += m * W.w;
        m = f1.y * wr1.y; W = wp[5]; a0 += m * W.x; a1 += m * W.y; a2 += m * W.z; a3 += m * W.w;
        m = f1.z * wr1.z; W = wp[6]; a0 += m * W.x; a1 += m * W.y; a2 += m * W.z; a3 += m * W.w;
        m = f1.w * wr1.w; W = wp[7]; a0 += m * W.x; a1 += m * W.y; a2 += m * W.z; a3 += m * W.w;
      }
    }
    // reduce within each 16-lane row group (offsets 1,2,4,8 stay in-group)
    for (int off = 1; off < 16; off <<= 1) {
      a0 += __shfl_xor(a0, off);
      a1 += __shfl_xor(a1, off);
      a2 += __shfl_xor(a2, off);
      a3 += __shfl_xor(a3, off);
    }
    int i = i0 + sub;
    if (cl == 0 && i < N) ((float4*)y)[i] = make_float4(a0, a1, a2, a3);
    if (i < N) {
      s0 += a0; s1 += a1; s2 += a2; s3 += a3;
      q0 += a0 * a0; q1 += a1 * a1; q2 += a2 * a2; q3 += a3 * a3;
    }
  }
  // combine the 4 row-group partials (all lanes converged here)
  s0 += __shfl_xor(s0, 16); s0 += __shfl_xor(s0, 32);
  s1 += __shfl_xor(s1, 16); s1 += __shfl_xor(s1, 32);
  s2 += __shfl_xor(s2, 16); s2 += __shfl_xor(s2, 32);
  s3 += __shfl_xor(s3, 16); s3 += __shfl_xor(s3, 32);
  q0 += __shfl_xor(q0, 16); q0 += __shfl_xor(q0, 32);
  q1 += __shfl_xor(q1, 16); q1 += __shfl_xor(q1, 32);
  q2 += __shfl_xor(q2, 16); q2 += __shfl_xor(q2, 32);
  q3 += __shfl_xor(q3, 16); q3 += __shfl_xor(q3, 32);
  if (lane == 0) {
    float* p = bnpart + (size_t)gwave * 8;
    p[0] = s0; p[1] = s1; p[2] = s2; p[3] = s3;
    p[4] = q0; p[5] = q1; p[6] = q2; p[7] = q3;
  }
}

// ---------------------------------------------------------------- BN stat reduce -> scale/shift
__global__ void bn_reduce_kernel(const float* __restrict__ bnpart, int nparts,
                                 const float* __restrict__ gamma, const float* __restrict__ beta,
                                 float* __restrict__ scsh, int N) {
  __shared__ float red[256 * 8];
  int t = threadIdx.x;
  float S[8];
#pragma unroll
  for (int o = 0; o < 8; ++o) S[o] = 0.f;
  for (int i = t; i < nparts; i += 256) {
#pragma unroll
    for (int o = 0; o < 8; ++o) S[o] += bnpart[(size_t)i * 8 + o];
  }
#pragma unroll
  for (int o = 0; o < 8; ++o) red[t * 8 + o] = S[o];
  __syncthreads();
  for (int st = 128; st > 0; st >>= 1) {
    if (t < st) {
#pragma unroll
      for (int o = 0; o < 8; ++o) red[t * 8 + o] += red[(t + st) * 8 + o];
    }
    __syncthreads();
  }
  if (t == 0) {
    float invN = 1.f / (float)N;
#pragma unroll
    for (int o = 0; o < 4; ++o) {
      float mu = red[o] * invN;
      float var = red[4 + o] * invN - mu * mu;
      float sc = gamma[o] * rsqrtf(var + BN_EPS);
      scsh[o] = sc;
      scsh[4 + o] = beta[o] - mu * sc;
    }
  }
}

// ---------------------------------------------------------------- fused epilogue
// out = feats * (1 + w[b,c] * (1 + sigmoid(max_p z_p)))   [sigmoid is monotone]
__global__ void final_kernel(const float* __restrict__ feats, const float* __restrict__ wgt,
                             const float* __restrict__ y, const float* __restrict__ scsh,
                             const float* __restrict__ c2, float* __restrict__ out,
                             int N, int NPER) {
  int lane = threadIdx.x & 63;
  int gwave = blockIdx.x * (blockDim.x >> 6) + (threadIdx.x >> 6);
  int nwaves = gridDim.x * (blockDim.x >> 6);
  int rpw = (N + nwaves - 1) / nwaves;
  int rbeg = gwave * rpw, rend = min(N, rbeg + rpw);
  float4 sc = *(const float4*)scsh;
  float4 sh = *(const float4*)(scsh + 4);
  float4 r0 = *(const float4*)(c2 + 0);
  float4 r1 = *(const float4*)(c2 + 4);
  float4 r2 = *(const float4*)(c2 + 8);
  float4 r3 = *(const float4*)(c2 + 12);
  for (int i = rbeg; i < rend; ++i) {
    float4 yv = *(const float4*)(y + (size_t)i * 4);
    float y0 = fmaxf(yv.x * sc.x + sh.x, 0.f);
    float y1 = fmaxf(yv.y * sc.y + sh.y, 0.f);
    float y2 = fmaxf(yv.z * sc.z + sh.z, 0.f);
    float y3 = fmaxf(yv.w * sc.w + sh.w, 0.f);
    float z0 = y0 * r0.x + y1 * r1.x + y2 * r2.x + y3 * r3.x;
    float z1 = y0 * r0.y + y1 * r1.y + y2 * r2.y + y3 * r3.y;
    float z2 = y0 * r0.z + y1 * r1.z + y2 * r2.z + y3 * r3.z;
    float z3 = y0 * r0.w + y1 * r1.w + y2 * r2.w + y3 * r3.w;
    float zm = fmaxf(fmaxf(z0, z1), fmaxf(z2, z3));
    float gate = 1.f / (1.f + expf(-zm));
    float g1 = 1.f + gate;
    int b = i / NPER;
    float2 w = *(const float2*)(wgt + b * C + 2 * lane);
    float2 f = *(const float2*)(feats + (size_t)i * C + 2 * lane);
    float2 o2;
    o2.x = f.x * (1.f + w.x * g1);
    o2.y = f.y * (1.f + w.y * g1);
    *(float2*)(out + (size_t)i * C + 2 * lane) = o2;
  }
}

extern "C" void kernel_launch(void* const* d_in, const int* in_sizes, int n_in,
                              void* d_out, int out_size, void* d_ws, size_t ws_size,
                              hipStream_t stream) {
  const float* feats   = (const float*)d_in[0];
  const float* w1      = (const float*)d_in[1];
  const float* b1      = (const float*)d_in[2];
  const float* w2      = (const float*)d_in[3];
  const float* b2      = (const float*)d_in[4];
  const float* conv1w  = (const float*)d_in[5];
  const float* gamma   = (const float*)d_in[6];
  const float* beta    = (const float*)d_in[7];
  const float* c2      = (const float*)d_in[8];
  const int*   nbr_idx = (const int*)d_in[9];
  const void*  nbr_mask = d_in[10];
  int N = in_sizes[0] / C;
  int NPER = N / BATCHES;

  char* ws = (char*)d_ws;
  size_t off = 0;
  int* flag = (int*)(ws + off);        off += 16;
  float* psum = (float*)(ws + off);    off += (size_t)BATCHES * CHUNKS * 2 * C * 4;
  float* pmax = (float*)(ws + off);    off += (size_t)BATCHES * CHUNKS * 2 * C * 4;
  float* avg  = (float*)(ws + off);    off += (size_t)BATCHES * C * 4;
  float* mx   = (float*)(ws + off);    off += (size_t)BATCHES * C * 4;
  float* wgt  = (float*)(ws + off);    off += (size_t)BATCHES * C * 4;
  float* y    = (float*)(ws + off);    off += (size_t)N * 4 * 4;
  float* bnpart = (float*)(ws + off);  off += (size_t)NWAVES_CONV * 8 * 4;
  float* scsh = (float*)(ws + off);    off += 64;
  float* outp = (float*)d_out;

  int nwords = (N * K) / 4;
  if (nwords > (1 << 20)) nwords = 1 << 20;  // byte-mode evidence is dense & early
  hipMemsetAsync(flag, 0, sizeof(int), stream);
  detect_mask_kernel<<<64, 256, 0, stream>>>((const unsigned int*)nbr_mask, nwords, flag);
  reduceA_kernel<<<BATCHES * CHUNKS, 256, 0, stream>>>(feats, psum, pmax, NPER);
  reduceB_kernel<<<BATCHES, 256, 0, stream>>>(psum, pmax, avg, mx, NPER);
  mlp_kernel<<<BATCHES, C, 0, stream>>>(avg, mx, w1, b1, w2, b2, wgt);
  conv_kernel<<<CONV_BLOCKS, CONV_TPB, 0, stream>>>(feats, wgt, conv1w, nbr_idx, nbr_mask,
                                                    flag, y, bnpart, N, NPER);
  bn_reduce_kernel<<<1, 256, 0, stream>>>(bnpart, NWAVES_CONV, gamma, beta, scsh, N);
  final_kernel<<<2048, 256, 0, stream>>>(feats, wgt, y, scsh, c2, outp, N, NPER);
}

// Round 4
// 234.937 us; speedup vs baseline: 1.7024x; 1.7024x over previous
//
#include <hip/hip_runtime.h>

#define C 128
#define K 27
#define BATCHES 4
#define CHUNKS 256            // stage-A chunks per batch
#define CONV_BLOCKS 512
#define CONV_TPB 1024
#define NWAVES_CONV (CONV_BLOCKS * (CONV_TPB / 64))   // 8192
#define BN_EPS 1e-5f

// ---------------------------------------------------------------- mask dtype probe
// If nbr_mask is stored as 1-byte bools, words in the early region exceed 1
// (center offset k=13 is always true). If int32, every word is 0 or 1.
__global__ void detect_mask_kernel(const unsigned int* __restrict__ w, int nwords,
                                   int* __restrict__ flag) {
  int stride = gridDim.x * blockDim.x;
  bool bad = false;
  for (int i = blockIdx.x * blockDim.x + threadIdx.x; i < nwords; i += stride)
    bad |= (w[i] > 1u);
  if (__any(bad) && (threadIdx.x & 63) == 0) atomicOr(flag, 1);
}

// ---------------------------------------------------------------- per-batch sum/max, stage A
__global__ void reduceA_kernel(const float* __restrict__ feats, float* __restrict__ psum,
                               float* __restrict__ pmax, int NPER) {
  int b = blockIdx.x / CHUNKS, chunk = blockIdx.x % CHUNKS;
  int CH = (NPER + CHUNKS - 1) / CHUNKS;
  int r0 = b * NPER + chunk * CH;
  int r1 = min(b * NPER + NPER, r0 + CH);
  int c = threadIdx.x;  // 128 threads = one channel each
  float s = 0.f, m = -INFINITY;
  for (int i = r0; i < r1; ++i) {
    float v = feats[(size_t)i * C + c];
    s += v;
    m = fmaxf(m, v);
  }
  psum[(size_t)blockIdx.x * C + c] = s;
  pmax[(size_t)blockIdx.x * C + c] = m;
}

// ---------------------------------------------------------------- stage B
__global__ void reduceB_kernel(const float* __restrict__ psum, const float* __restrict__ pmax,
                               float* __restrict__ avg, float* __restrict__ mx, int NPER) {
  int b = blockIdx.x, c = threadIdx.x;
  float s = 0.f, m = -INFINITY;
  for (int j = 0; j < CHUNKS; ++j) {
    s += psum[(size_t)(b * CHUNKS + j) * C + c];
    m = fmaxf(m, pmax[(size_t)(b * CHUNKS + j) * C + c]);
  }
  avg[b * C + c] = s / (float)NPER;
  mx[b * C + c] = m;
}

// ---------------------------------------------------------------- channel-attention MLP
__global__ void mlp_kernel(const float* __restrict__ avg, const float* __restrict__ mx,
                           const float* __restrict__ w1, const float* __restrict__ b1,
                           const float* __restrict__ w2, const float* __restrict__ b2,
                           float* __restrict__ wgt) {
  int b = blockIdx.x, t = threadIdx.x;  // 128 threads
  __shared__ float h1a[64], h1m[64];
  if (t < 64) {
    float sa = b1[t], sm = b1[t];
    for (int c = 0; c < C; ++c) {
      float wv = w1[c * 64 + t];
      sa += avg[b * C + c] * wv;
      sm += mx[b * C + c] * wv;
    }
    h1a[t] = fmaxf(sa, 0.f);
    h1m[t] = fmaxf(sm, 0.f);
  }
  __syncthreads();
  float za = b2[t], zm = b2[t];
  for (int h = 0; h < 64; ++h) {
    float wv = w2[h * C + t];
    za += h1a[h] * wv;
    zm += h1m[h] * wv;
  }
  float z = za + zm;
  wgt[b * C + t] = 1.f / (1.f + expf(-z));
}

// ---------------------------------------------------------------- sparse 3x3x3 conv C->4 + BN partials
// One row per 64-lane wave, 2 channels/lane. Ballot is wave-uniform -> every
// branch below is wave-uniform; shuffles always run with all 64 lanes active.
// Weights live in LDS (staged once per 16-wave block). First 4 neighbor
// gathers are issued back-to-back (4 outstanding loads); rare >4 tail loops.
__global__ __launch_bounds__(CONV_TPB, 8) void conv_kernel(
    const float* __restrict__ feats, const float* __restrict__ wgt,
    const float* __restrict__ conv1_w, const int* __restrict__ nbr_idx,
    const void* __restrict__ nbr_mask, const int* __restrict__ flagp,
    float* __restrict__ y, float* __restrict__ bnpart, int N, int NPER) {
  __shared__ float wlds[K * C * 4];  // 13824 floats = 54 KiB
  int tid = threadIdx.x;
  for (int i = tid; i < K * C; i += CONV_TPB)   // K*C float4 slots
    ((float4*)wlds)[i] = ((const float4*)conv1_w)[i];
  __syncthreads();

  int lane = tid & 63;
  int gwave = blockIdx.x * (CONV_TPB / 64) + (tid >> 6);
  int nwaves = gridDim.x * (CONV_TPB / 64);
  int rpw = (N + nwaves - 1) / nwaves;
  int rbeg = gwave * rpw, rend = min(N, rbeg + rpw);
  bool byteMode = (*flagp != 0);
  const unsigned char* mb = (const unsigned char*)nbr_mask;
  const int* mi = (const int*)nbr_mask;

  int b = min(rbeg / NPER, BATCHES - 1);
  float2 wr = *(const float2*)(wgt + b * C + 2 * lane);

  // prefetch first row's mask/idx
  bool mk = false;
  int jl = 0;
  if (rbeg < rend && lane < K) {
    size_t e = (size_t)rbeg * K + lane;
    mk = byteMode ? (mb[e] != 0) : (mi[e] != 0);
    jl = nbr_idx[e];
  }

  float s0 = 0, s1 = 0, s2 = 0, s3 = 0, q0 = 0, q1 = 0, q2 = 0, q3 = 0;

  for (int i = rbeg; i < rend; ++i) {
    unsigned long long bal = __ballot(mk);
    int jcur = jl;
    // prefetch next row (hidden under this row's gathers)
    mk = false;
    if (i + 1 < rend && lane < K) {
      size_t e = (size_t)(i + 1) * K + lane;
      mk = byteMode ? (mb[e] != 0) : (mi[e] != 0);
      jl = nbr_idx[e];
    }
    if (i >= (b + 1) * NPER && b < BATCHES - 1) {
      ++b;
      wr = *(const float2*)(wgt + b * C + 2 * lane);
    }
    int cnt = __popcll(bal);
    int k0 = __ffsll(bal) - 1; bal &= bal - 1;
    int k1 = __ffsll(bal) - 1; bal &= bal - 1;
    int k2 = __ffsll(bal) - 1; bal &= bal - 1;
    int k3 = __ffsll(bal) - 1; bal &= bal - 1;
    int j0 = __shfl(jcur, k0 & 63);
    int j1 = __shfl(jcur, k1 & 63);
    int j2 = __shfl(jcur, k2 & 63);
    int j3 = __shfl(jcur, k3 & 63);
    // issue up to 4 gathers back-to-back (cnt is wave-uniform -> no divergence)
    float2 f0 = make_float2(0.f, 0.f), f1 = f0, f2 = f0, f3 = f0;
    if (cnt > 0) f0 = *(const float2*)(feats + (size_t)j0 * C + 2 * lane);
    if (cnt > 1) f1 = *(const float2*)(feats + (size_t)j1 * C + 2 * lane);
    if (cnt > 2) f2 = *(const float2*)(feats + (size_t)j2 * C + 2 * lane);
    if (cnt > 3) f3 = *(const float2*)(feats + (size_t)j3 * C + 2 * lane);
    float a0 = 0, a1 = 0, a2 = 0, a3 = 0;
#define ACC(ff, kk)                                                     \
    {                                                                   \
      const float4* wp = (const float4*)(wlds + (kk)*C * 4 + lane * 8); \
      float4 c0 = wp[0], c1 = wp[1];                                    \
      float m0 = ff.x * wr.x, m1 = ff.y * wr.y;                         \
      a0 += m0 * c0.x + m1 * c1.x;                                      \
      a1 += m0 * c0.y + m1 * c1.y;                                      \
      a2 += m0 * c0.z + m1 * c1.z;                                      \
      a3 += m0 * c0.w + m1 * c1.w;                                      \
    }
    if (cnt > 0) ACC(f0, k0)
    if (cnt > 1) ACC(f1, k1)
    if (cnt > 2) ACC(f2, k2)
    if (cnt > 3) ACC(f3, k3)
    while (bal) {  // rare tail (cnt > 4), still wave-uniform
      int kk = __ffsll(bal) - 1; bal &= bal - 1;
      int j = __shfl(jcur, kk);
      float2 f = *(const float2*)(feats + (size_t)j * C + 2 * lane);
      ACC(f, kk)
    }
#undef ACC
    // butterfly: every lane ends with the full channel sum
    for (int off = 1; off < 64; off <<= 1) {
      a0 += __shfl_xor(a0, off);
      a1 += __shfl_xor(a1, off);
      a2 += __shfl_xor(a2, off);
      a3 += __shfl_xor(a3, off);
    }
    if (lane == 0) ((float4*)y)[i] = make_float4(a0, a1, a2, a3);
    s0 += a0; s1 += a1; s2 += a2; s3 += a3;
    q0 += a0 * a0; q1 += a1 * a1; q2 += a2 * a2; q3 += a3 * a3;
  }
  if (lane == 0) {
    float* p = bnpart + (size_t)gwave * 8;
    p[0] = s0; p[1] = s1; p[2] = s2; p[3] = s3;
    p[4] = q0; p[5] = q1; p[6] = q2; p[7] = q3;
  }
}

// ---------------------------------------------------------------- BN stat reduce -> scale/shift
__global__ void bn_reduce_kernel(const float* __restrict__ bnpart, int nparts,
                                 const float* __restrict__ gamma, const float* __restrict__ beta,
                                 float* __restrict__ scsh, int N) {
  __shared__ float red[256 * 8];
  int t = threadIdx.x;
  float S[8];
#pragma unroll
  for (int o = 0; o < 8; ++o) S[o] = 0.f;
  for (int i = t; i < nparts; i += 256) {
#pragma unroll
    for (int o = 0; o < 8; ++o) S[o] += bnpart[(size_t)i * 8 + o];
  }
#pragma unroll
  for (int o = 0; o < 8; ++o) red[t * 8 + o] = S[o];
  __syncthreads();
  for (int st = 128; st > 0; st >>= 1) {
    if (t < st) {
#pragma unroll
      for (int o = 0; o < 8; ++o) red[t * 8 + o] += red[(t + st) * 8 + o];
    }
    __syncthreads();
  }
  if (t == 0) {
    float invN = 1.f / (float)N;
#pragma unroll
    for (int o = 0; o < 4; ++o) {
      float mu = red[o] * invN;
      float var = red[4 + o] * invN - mu * mu;
      float sc = gamma[o] * rsqrtf(var + BN_EPS);
      scsh[o] = sc;
      scsh[4 + o] = beta[o] - mu * sc;
    }
  }
}

// ---------------------------------------------------------------- fused epilogue
// out = feats * (1 + w[b,c] * (1 + sigmoid(max_p z_p)))   [sigmoid is monotone]
__global__ void final_kernel(const float* __restrict__ feats, const float* __restrict__ wgt,
                             const float* __restrict__ y, const float* __restrict__ scsh,
                             const float* __restrict__ c2, float* __restrict__ out,
                             int N, int NPER) {
  int lane = threadIdx.x & 63;
  int gwave = blockIdx.x * (blockDim.x >> 6) + (threadIdx.x >> 6);
  int nwaves = gridDim.x * (blockDim.x >> 6);
  int rpw = (N + nwaves - 1) / nwaves;
  int rbeg = gwave * rpw, rend = min(N, rbeg + rpw);
  float4 sc = *(const float4*)scsh;
  float4 sh = *(const float4*)(scsh + 4);
  float4 r0 = *(const float4*)(c2 + 0);
  float4 r1 = *(const float4*)(c2 + 4);
  float4 r2 = *(const float4*)(c2 + 8);
  float4 r3 = *(const float4*)(c2 + 12);
  for (int i = rbeg; i < rend; ++i) {
    float4 yv = *(const float4*)(y + (size_t)i * 4);
    float y0 = fmaxf(yv.x * sc.x + sh.x, 0.f);
    float y1 = fmaxf(yv.y * sc.y + sh.y, 0.f);
    float y2 = fmaxf(yv.z * sc.z + sh.z, 0.f);
    float y3 = fmaxf(yv.w * sc.w + sh.w, 0.f);
    float z0 = y0 * r0.x + y1 * r1.x + y2 * r2.x + y3 * r3.x;
    float z1 = y0 * r0.y + y1 * r1.y + y2 * r2.y + y3 * r3.y;
    float z2 = y0 * r0.z + y1 * r1.z + y2 * r2.z + y3 * r3.z;
    float z3 = y0 * r0.w + y1 * r1.w + y2 * r2.w + y3 * r3.w;
    float zm = fmaxf(fmaxf(z0, z1), fmaxf(z2, z3));
    float gate = 1.f / (1.f + expf(-zm));
    float g1 = 1.f + gate;
    int b = i / NPER;
    float2 w = *(const float2*)(wgt + b * C + 2 * lane);
    float2 f = *(const float2*)(feats + (size_t)i * C + 2 * lane);
    float2 o2;
    o2.x = f.x * (1.f + w.x * g1);
    o2.y = f.y * (1.f + w.y * g1);
    *(float2*)(out + (size_t)i * C + 2 * lane) = o2;
  }
}

extern "C" void kernel_launch(void* const* d_in, const int* in_sizes, int n_in,
                              void* d_out, int out_size, void* d_ws, size_t ws_size,
                              hipStream_t stream) {
  const float* feats   = (const float*)d_in[0];
  const float* w1      = (const float*)d_in[1];
  const float* b1      = (const float*)d_in[2];
  const float* w2      = (const float*)d_in[3];
  const float* b2      = (const float*)d_in[4];
  const float* conv1w  = (const float*)d_in[5];
  const float* gamma   = (const float*)d_in[6];
  const float* beta    = (const float*)d_in[7];
  const float* c2      = (const float*)d_in[8];
  const int*   nbr_idx = (const int*)d_in[9];
  const void*  nbr_mask = d_in[10];
  int N = in_sizes[0] / C;
  int NPER = N / BATCHES;

  char* ws = (char*)d_ws;
  size_t off = 0;
  int* flag = (int*)(ws + off);        off += 16;
  float* psum = (float*)(ws + off);    off += (size_t)BATCHES * CHUNKS * C * 4;
  float* pmax = (float*)(ws + off);    off += (size_t)BATCHES * CHUNKS * C * 4;
  float* avg  = (float*)(ws + off);    off += (size_t)BATCHES * C * 4;
  float* mx   = (float*)(ws + off);    off += (size_t)BATCHES * C * 4;
  float* wgt  = (float*)(ws + off);    off += (size_t)BATCHES * C * 4;
  float* y    = (float*)(ws + off);    off += (size_t)N * 4 * 4;
  float* bnpart = (float*)(ws + off);  off += (size_t)NWAVES_CONV * 8 * 4;
  float* scsh = (float*)(ws + off);    off += 64;
  float* outp = (float*)d_out;

  int nwords = (N * K) / 4;
  if (nwords > (1 << 20)) nwords = 1 << 20;  // byte-mode evidence is dense & early
  hipMemsetAsync(flag, 0, sizeof(int), stream);
  detect_mask_kernel<<<64, 256, 0, stream>>>((const unsigned int*)nbr_mask, nwords, flag);
  reduceA_kernel<<<BATCHES * CHUNKS, C, 0, stream>>>(feats, psum, pmax, NPER);
  reduceB_kernel<<<BATCHES, C, 0, stream>>>(psum, pmax, avg, mx, NPER);
  mlp_kernel<<<BATCHES, C, 0, stream>>>(avg, mx, w1, b1, w2, b2, wgt);
  conv_kernel<<<CONV_BLOCKS, CONV_TPB, 0, stream>>>(feats, wgt, conv1w, nbr_idx, nbr_mask,
                                                    flag, y, bnpart, N, NPER);
  bn_reduce_kernel<<<1, 256, 0, stream>>>(bnpart, NWAVES_CONV, gamma, beta, scsh, N);
  final_kernel<<<2048, 256, 0, stream>>>(feats, wgt, y, scsh, c2, outp, N, NPER);
}

// Round 5
// 199.469 us; speedup vs baseline: 2.0051x; 1.1778x over previous
//
#include <hip/hip_runtime.h>

#define C 128
#define K 27
#define BATCHES 4
#define RA_BPB 512            // stage-A blocks per batch
#define CONV_BLOCKS 512
#define CONV_TPB 1024
#define NWAVES_CONV (CONV_BLOCKS * (CONV_TPB / 64))   // 8192
#define BN_EPS 1e-5f

// ---------------------------------------------------------------- mask dtype probe
__global__ void detect_mask_kernel(const unsigned int* __restrict__ w, int nwords,
                                   int* __restrict__ flag) {
  int stride = gridDim.x * blockDim.x;
  bool bad = false;
  for (int i = blockIdx.x * blockDim.x + threadIdx.x; i < nwords; i += stride)
    bad |= (w[i] > 1u);
  if (__any(bad) && (threadIdx.x & 63) == 0) atomicOr(flag, 1);
}

// ---------------------------------------------------------------- per-batch sum/max, stage A
// 2048 blocks x 256 threads: 8 row-groups x 32 lanes, float4 per lane.
// 8 independent row-loads in flight per block -> latency hidden; full device.
__global__ __launch_bounds__(256) void reduceA_kernel(
    const float* __restrict__ feats, float* __restrict__ psum,
    float* __restrict__ pmax, int NPER) {
  int b = blockIdx.x / RA_BPB, chunk = blockIdx.x % RA_BPB;
  int CH = (NPER + RA_BPB - 1) / RA_BPB;
  int r0 = b * NPER + chunk * CH;
  int r1 = min(b * NPER + NPER, r0 + CH);
  int g = threadIdx.x >> 5;   // 8 row groups
  int l = threadIdx.x & 31;   // lane -> channels 4l..4l+3
  float4 s = make_float4(0.f, 0.f, 0.f, 0.f);
  float4 m = make_float4(-INFINITY, -INFINITY, -INFINITY, -INFINITY);
  for (int i = r0 + g; i < r1; i += 8) {
    float4 v = *(const float4*)(feats + (size_t)i * C + l * 4);
    s.x += v.x; s.y += v.y; s.z += v.z; s.w += v.w;
    m.x = fmaxf(m.x, v.x); m.y = fmaxf(m.y, v.y);
    m.z = fmaxf(m.z, v.z); m.w = fmaxf(m.w, v.w);
  }
  __shared__ float ssum[8][C], smax[8][C];
  *(float4*)&ssum[g][l * 4] = s;
  *(float4*)&smax[g][l * 4] = m;
  __syncthreads();
  if (threadIdx.x < C) {
    int c = threadIdx.x;
    float S = 0.f, M = -INFINITY;
#pragma unroll
    for (int gg = 0; gg < 8; ++gg) {
      S += ssum[gg][c];
      M = fmaxf(M, smax[gg][c]);
    }
    psum[(size_t)blockIdx.x * C + c] = S;
    pmax[(size_t)blockIdx.x * C + c] = M;
  }
}

// ---------------------------------------------------------------- stage B
__global__ __launch_bounds__(256) void reduceB_kernel(
    const float* __restrict__ psum, const float* __restrict__ pmax,
    float* __restrict__ avg, float* __restrict__ mx, int NPER) {
  int b = blockIdx.x;
  int g = threadIdx.x >> 5, l = threadIdx.x & 31;
  float4 s = make_float4(0.f, 0.f, 0.f, 0.f);
  float4 m = make_float4(-INFINITY, -INFINITY, -INFINITY, -INFINITY);
  for (int j = g; j < RA_BPB; j += 8) {
    size_t base = (size_t)(b * RA_BPB + j) * C + l * 4;
    float4 vs = *(const float4*)(psum + base);
    float4 vm = *(const float4*)(pmax + base);
    s.x += vs.x; s.y += vs.y; s.z += vs.z; s.w += vs.w;
    m.x = fmaxf(m.x, vm.x); m.y = fmaxf(m.y, vm.y);
    m.z = fmaxf(m.z, vm.z); m.w = fmaxf(m.w, vm.w);
  }
  __shared__ float ssum[8][C], smax[8][C];
  *(float4*)&ssum[g][l * 4] = s;
  *(float4*)&smax[g][l * 4] = m;
  __syncthreads();
  if (threadIdx.x < C) {
    int c = threadIdx.x;
    float S = 0.f, M = -INFINITY;
#pragma unroll
    for (int gg = 0; gg < 8; ++gg) {
      S += ssum[gg][c];
      M = fmaxf(M, smax[gg][c]);
    }
    avg[b * C + c] = S / (float)NPER;
    mx[b * C + c] = M;
  }
}

// ---------------------------------------------------------------- channel-attention MLP
__global__ void mlp_kernel(const float* __restrict__ avg, const float* __restrict__ mx,
                           const float* __restrict__ w1, const float* __restrict__ b1,
                           const float* __restrict__ w2, const float* __restrict__ b2,
                           float* __restrict__ wgt) {
  int b = blockIdx.x, t = threadIdx.x;  // 128 threads
  __shared__ float h1a[64], h1m[64];
  if (t < 64) {
    float sa = b1[t], sm = b1[t];
    for (int c = 0; c < C; ++c) {
      float wv = w1[c * 64 + t];
      sa += avg[b * C + c] * wv;
      sm += mx[b * C + c] * wv;
    }
    h1a[t] = fmaxf(sa, 0.f);
    h1m[t] = fmaxf(sm, 0.f);
  }
  __syncthreads();
  float za = b2[t], zm = b2[t];
  for (int h = 0; h < 64; ++h) {
    float wv = w2[h * C + t];
    za += h1a[h] * wv;
    zm += h1m[h] * wv;
  }
  float z = za + zm;
  wgt[b * C + t] = 1.f / (1.f + expf(-z));
}

// ---------------------------------------------------------------- sparse 3x3x3 conv C->4 + BN partials
// One row per 64-lane wave, 2 channels/lane. Ballot is wave-uniform -> every
// branch below is wave-uniform; shuffles always run with all 64 lanes active.
// Weights live in LDS (staged once per 16-wave block). First 4 neighbor
// gathers are issued back-to-back (4 outstanding loads); rare >4 tail loops.
__global__ __launch_bounds__(CONV_TPB, 8) void conv_kernel(
    const float* __restrict__ feats, const float* __restrict__ wgt,
    const float* __restrict__ conv1_w, const int* __restrict__ nbr_idx,
    const void* __restrict__ nbr_mask, const int* __restrict__ flagp,
    float* __restrict__ y, float* __restrict__ bnpart, int N, int NPER) {
  __shared__ float wlds[K * C * 4];  // 13824 floats = 54 KiB
  int tid = threadIdx.x;
  for (int i = tid; i < K * C; i += CONV_TPB)   // K*C float4 slots
    ((float4*)wlds)[i] = ((const float4*)conv1_w)[i];
  __syncthreads();

  int lane = tid & 63;
  int gwave = blockIdx.x * (CONV_TPB / 64) + (tid >> 6);
  int nwaves = gridDim.x * (CONV_TPB / 64);
  int rpw = (N + nwaves - 1) / nwaves;
  int rbeg = gwave * rpw, rend = min(N, rbeg + rpw);
  bool byteMode = (*flagp != 0);
  const unsigned char* mb = (const unsigned char*)nbr_mask;
  const int* mi = (const int*)nbr_mask;

  int b = min(rbeg / NPER, BATCHES - 1);
  float2 wr = *(const float2*)(wgt + b * C + 2 * lane);

  // prefetch first row's mask/idx
  bool mk = false;
  int jl = 0;
  if (rbeg < rend && lane < K) {
    size_t e = (size_t)rbeg * K + lane;
    mk = byteMode ? (mb[e] != 0) : (mi[e] != 0);
    jl = nbr_idx[e];
  }

  float s0 = 0, s1 = 0, s2 = 0, s3 = 0, q0 = 0, q1 = 0, q2 = 0, q3 = 0;

  for (int i = rbeg; i < rend; ++i) {
    unsigned long long bal = __ballot(mk);
    int jcur = jl;
    // prefetch next row (hidden under this row's gathers)
    mk = false;
    if (i + 1 < rend && lane < K) {
      size_t e = (size_t)(i + 1) * K + lane;
      mk = byteMode ? (mb[e] != 0) : (mi[e] != 0);
      jl = nbr_idx[e];
    }
    if (i >= (b + 1) * NPER && b < BATCHES - 1) {
      ++b;
      wr = *(const float2*)(wgt + b * C + 2 * lane);
    }
    int cnt = __popcll(bal);
    int k0 = __ffsll(bal) - 1; bal &= bal - 1;
    int k1 = __ffsll(bal) - 1; bal &= bal - 1;
    int k2 = __ffsll(bal) - 1; bal &= bal - 1;
    int k3 = __ffsll(bal) - 1; bal &= bal - 1;
    int j0 = __shfl(jcur, k0 & 63);
    int j1 = __shfl(jcur, k1 & 63);
    int j2 = __shfl(jcur, k2 & 63);
    int j3 = __shfl(jcur, k3 & 63);
    // issue up to 4 gathers back-to-back (cnt is wave-uniform -> no divergence)
    float2 f0 = make_float2(0.f, 0.f), f1 = f0, f2 = f0, f3 = f0;
    if (cnt > 0) f0 = *(const float2*)(feats + (size_t)j0 * C + 2 * lane);
    if (cnt > 1) f1 = *(const float2*)(feats + (size_t)j1 * C + 2 * lane);
    if (cnt > 2) f2 = *(const float2*)(feats + (size_t)j2 * C + 2 * lane);
    if (cnt > 3) f3 = *(const float2*)(feats + (size_t)j3 * C + 2 * lane);
    float a0 = 0, a1 = 0, a2 = 0, a3 = 0;
#define ACC(ff, kk)                                                     \
    {                                                                   \
      const float4* wp = (const float4*)(wlds + (kk)*C * 4 + lane * 8); \
      float4 c0 = wp[0], c1 = wp[1];                                    \
      float m0 = ff.x * wr.x, m1 = ff.y * wr.y;                         \
      a0 += m0 * c0.x + m1 * c1.x;                                      \
      a1 += m0 * c0.y + m1 * c1.y;                                      \
      a2 += m0 * c0.z + m1 * c1.z;                                      \
      a3 += m0 * c0.w + m1 * c1.w;                                      \
    }
    if (cnt > 0) ACC(f0, k0)
    if (cnt > 1) ACC(f1, k1)
    if (cnt > 2) ACC(f2, k2)
    if (cnt > 3) ACC(f3, k3)
    while (bal) {  // rare tail (cnt > 4), still wave-uniform
      int kk = __ffsll(bal) - 1; bal &= bal - 1;
      int j = __shfl(jcur, kk);
      float2 f = *(const float2*)(feats + (size_t)j * C + 2 * lane);
      ACC(f, kk)
    }
#undef ACC
    // butterfly: every lane ends with the full channel sum
    for (int off = 1; off < 64; off <<= 1) {
      a0 += __shfl_xor(a0, off);
      a1 += __shfl_xor(a1, off);
      a2 += __shfl_xor(a2, off);
      a3 += __shfl_xor(a3, off);
    }
    if (lane == 0) ((float4*)y)[i] = make_float4(a0, a1, a2, a3);
    s0 += a0; s1 += a1; s2 += a2; s3 += a3;
    q0 += a0 * a0; q1 += a1 * a1; q2 += a2 * a2; q3 += a3 * a3;
  }
  if (lane == 0) {
    float* p = bnpart + (size_t)gwave * 8;
    p[0] = s0; p[1] = s1; p[2] = s2; p[3] = s3;
    p[4] = q0; p[5] = q1; p[6] = q2; p[7] = q3;
  }
}

// ---------------------------------------------------------------- BN stat reduce -> scale/shift
__global__ void bn_reduce_kernel(const float* __restrict__ bnpart, int nparts,
                                 const float* __restrict__ gamma, const float* __restrict__ beta,
                                 float* __restrict__ scsh, int N) {
  __shared__ float red[256 * 8];
  int t = threadIdx.x;
  float S[8];
#pragma unroll
  for (int o = 0; o < 8; ++o) S[o] = 0.f;
  for (int i = t; i < nparts; i += 256) {
#pragma unroll
    for (int o = 0; o < 8; ++o) S[o] += bnpart[(size_t)i * 8 + o];
  }
#pragma unroll
  for (int o = 0; o < 8; ++o) red[t * 8 + o] = S[o];
  __syncthreads();
  for (int st = 128; st > 0; st >>= 1) {
    if (t < st) {
#pragma unroll
      for (int o = 0; o < 8; ++o) red[t * 8 + o] += red[(t + st) * 8 + o];
    }
    __syncthreads();
  }
  if (t == 0) {
    float invN = 1.f / (float)N;
#pragma unroll
    for (int o = 0; o < 4; ++o) {
      float mu = red[o] * invN;
      float var = red[4 + o] * invN - mu * mu;
      float sc = gamma[o] * rsqrtf(var + BN_EPS);
      scsh[o] = sc;
      scsh[4 + o] = beta[o] - mu * sc;
    }
  }
}

// ---------------------------------------------------------------- fused epilogue
// out = feats * (1 + w[b,c] * (1 + sigmoid(max_p z_p)))   [sigmoid is monotone]
__global__ void final_kernel(const float* __restrict__ feats, const float* __restrict__ wgt,
                             const float* __restrict__ y, const float* __restrict__ scsh,
                             const float* __restrict__ c2, float* __restrict__ out,
                             int N, int NPER) {
  int lane = threadIdx.x & 63;
  int gwave = blockIdx.x * (blockDim.x >> 6) + (threadIdx.x >> 6);
  int nwaves = gridDim.x * (blockDim.x >> 6);
  int rpw = (N + nwaves - 1) / nwaves;
  int rbeg = gwave * rpw, rend = min(N, rbeg + rpw);
  float4 sc = *(const float4*)scsh;
  float4 sh = *(const float4*)(scsh + 4);
  float4 r0 = *(const float4*)(c2 + 0);
  float4 r1 = *(const float4*)(c2 + 4);
  float4 r2 = *(const float4*)(c2 + 8);
  float4 r3 = *(const float4*)(c2 + 12);
  for (int i = rbeg; i < rend; ++i) {
    float4 yv = *(const float4*)(y + (size_t)i * 4);
    float y0 = fmaxf(yv.x * sc.x + sh.x, 0.f);
    float y1 = fmaxf(yv.y * sc.y + sh.y, 0.f);
    float y2 = fmaxf(yv.z * sc.z + sh.z, 0.f);
    float y3 = fmaxf(yv.w * sc.w + sh.w, 0.f);
    float z0 = y0 * r0.x + y1 * r1.x + y2 * r2.x + y3 * r3.x;
    float z1 = y0 * r0.y + y1 * r1.y + y2 * r2.y + y3 * r3.y;
    float z2 = y0 * r0.z + y1 * r1.z + y2 * r2.z + y3 * r3.z;
    float z3 = y0 * r0.w + y1 * r1.w + y2 * r2.w + y3 * r3.w;
    float zm = fmaxf(fmaxf(z0, z1), fmaxf(z2, z3));
    float gate = 1.f / (1.f + expf(-zm));
    float g1 = 1.f + gate;
    int b = i / NPER;
    float2 w = *(const float2*)(wgt + b * C + 2 * lane);
    float2 f = *(const float2*)(feats + (size_t)i * C + 2 * lane);
    float2 o2;
    o2.x = f.x * (1.f + w.x * g1);
    o2.y = f.y * (1.f + w.y * g1);
    *(float2*)(out + (size_t)i * C + 2 * lane) = o2;
  }
}

extern "C" void kernel_launch(void* const* d_in, const int* in_sizes, int n_in,
                              void* d_out, int out_size, void* d_ws, size_t ws_size,
                              hipStream_t stream) {
  const float* feats   = (const float*)d_in[0];
  const float* w1      = (const float*)d_in[1];
  const float* b1      = (const float*)d_in[2];
  const float* w2      = (const float*)d_in[3];
  const float* b2      = (const float*)d_in[4];
  const float* conv1w  = (const float*)d_in[5];
  const float* gamma   = (const float*)d_in[6];
  const float* beta    = (const float*)d_in[7];
  const float* c2      = (const float*)d_in[8];
  const int*   nbr_idx = (const int*)d_in[9];
  const void*  nbr_mask = d_in[10];
  int N = in_sizes[0] / C;
  int NPER = N / BATCHES;

  char* ws = (char*)d_ws;
  size_t off = 0;
  int* flag = (int*)(ws + off);        off += 16;
  float* psum = (float*)(ws + off);    off += (size_t)BATCHES * RA_BPB * C * 4;
  float* pmax = (float*)(ws + off);    off += (size_t)BATCHES * RA_BPB * C * 4;
  float* avg  = (float*)(ws + off);    off += (size_t)BATCHES * C * 4;
  float* mx   = (float*)(ws + off);    off += (size_t)BATCHES * C * 4;
  float* wgt  = (float*)(ws + off);    off += (size_t)BATCHES * C * 4;
  float* y    = (float*)(ws + off);    off += (size_t)N * 4 * 4;
  float* bnpart = (float*)(ws + off);  off += (size_t)NWAVES_CONV * 8 * 4;
  float* scsh = (float*)(ws + off);    off += 64;
  float* outp = (float*)d_out;

  int nwords = (N * K) / 4;
  if (nwords > (1 << 20)) nwords = 1 << 20;  // byte-mode evidence is dense & early
  hipMemsetAsync(flag, 0, sizeof(int), stream);
  detect_mask_kernel<<<64, 256, 0, stream>>>((const unsigned int*)nbr_mask, nwords, flag);
  reduceA_kernel<<<BATCHES * RA_BPB, 256, 0, stream>>>(feats, psum, pmax, NPER);
  reduceB_kernel<<<BATCHES, 256, 0, stream>>>(psum, pmax, avg, mx, NPER);
  mlp_kernel<<<BATCHES, C, 0, stream>>>(avg, mx, w1, b1, w2, b2, wgt);
  conv_kernel<<<CONV_BLOCKS, CONV_TPB, 0, stream>>>(feats, wgt, conv1w, nbr_idx, nbr_mask,
                                                    flag, y, bnpart, N, NPER);
  bn_reduce_kernel<<<1, 256, 0, stream>>>(bnpart, NWAVES_CONV, gamma, beta, scsh, N);
  final_kernel<<<2048, 256, 0, stream>>>(feats, wgt, y, scsh, c2, outp, N, NPER);
}